// Round 8
// baseline (31313.904 us; speedup 1.0000x reference)
//
#include <hip/hip_runtime.h>

namespace {
constexpr int TT   = 2048;
constexpr int NBLK = 128;
constexpr int RING = 4;
constexpr size_t YSZ = (size_t)32 * TT * 512;
constexpr size_t HFO = YSZ;
constexpr size_t CFO = YSZ + (size_t)2 * 32 * 512;
}

typedef float f32x4 __attribute__((ext_vector_type(4)));

__device__ __forceinline__ float sigf(float v)  { return 1.0f / (1.0f + __expf(-v)); }
__device__ __forceinline__ float tanh_(float v) { return 1.0f - 2.0f / (__expf(2.0f * v) + 1.0f); }

__device__ __forceinline__ void st_coh(float* p, float v) {
  __hip_atomic_store(p, v, __ATOMIC_RELAXED, __HIP_MEMORY_SCOPE_AGENT);
}
__device__ __forceinline__ void st_flag(int* p, int v) {
  __hip_atomic_store(p, v, __ATOMIC_RELAXED, __HIP_MEMORY_SCOPE_AGENT);
}
__device__ __forceinline__ void poll_lane(const int* f, int need) {
  while (__hip_atomic_load(f, __ATOMIC_RELAXED, __HIP_MEMORY_SCOPE_AGENT) < need)
    __builtin_amdgcn_s_sleep(1);
}

// global->LDS DMA, 16 B/lane; LDS dst = wave-uniform base + lane*16 (linear).
// _C: aux=0x11 (SC0|SC1) -> bypass L1/L2, read the shared coherence point
// (same semantics as the proven "global_load_dwordx4 ... sc1" register loads).
#define GLL_P(g, l) __builtin_amdgcn_global_load_lds(                         \
    (const __attribute__((address_space(1))) void*)(g),                       \
    (__attribute__((address_space(3))) void*)(l), 16, 0, 0)
#define GLL_C(g, l) __builtin_amdgcn_global_load_lds(                         \
    (const __attribute__((address_space(1))) void*)(g),                       \
    (__attribute__((address_space(3))) void*)(l), 16, 0, 0x11)

#define VMCNT4() do { asm volatile("s_waitcnt vmcnt(4)" ::: "memory"); __builtin_amdgcn_sched_barrier(0); } while (0)
#define VMCNT0() do { asm volatile("s_waitcnt vmcnt(0)" ::: "memory"); __builtin_amdgcn_sched_barrier(0); } while (0)
#define LGKM0()  do { asm volatile("s_waitcnt lgkmcnt(0)" ::: "memory"); __builtin_amdgcn_sched_barrier(0); } while (0)
#define BAR()    do { __builtin_amdgcn_s_barrier(); __builtin_amdgcn_sched_barrier(0); } while (0)

__global__ __launch_bounds__(512)
__attribute__((amdgpu_waves_per_eu(2, 2)))
void lstm_persist(
    const float* __restrict__ x,
    const float* __restrict__ Wih0, const float* __restrict__ Whh0,
    const float* __restrict__ bih0, const float* __restrict__ bhh0,
    const float* __restrict__ Wih1, const float* __restrict__ Whh1,
    const float* __restrict__ bih1, const float* __restrict__ bhh1,
    const float* __restrict__ h0c, const float* __restrict__ c0c,
    float* __restrict__ out, float* __restrict__ ring, float* __restrict__ ring1,
    int* __restrict__ flags0, int* __restrict__ flags1)
{
  // LDS: W' 64 KB + 2 input slots 2x32 KB + gbuf 2.1 KB = ~130 KB (1 block/CU).
  __shared__ __align__(16) float Wsh[16 * 1024];
  __shared__ __align__(16) float ubuf[2 * 32 * 256];
  __shared__ __align__(16) float gbuf[16 * 33];

  const int tid   = (int)threadIdx.x;
  const int layer = (int)(blockIdx.x >> 7);
  const int lb    = (int)(blockIdx.x & (NBLK - 1));
  const int j0    = lb << 2;
  const int lane  = tid & 63;
  const int wg    = tid >> 6;          // wave id 0..7
  const int k4    = lane << 2;         // this lane's f32x4 within a 256-k chunk
  const int R0    = (wg & 1) << 3;     // 8-row group
  const int B0    = (wg >> 1) << 3;    // 8-batch group

  const float* Wih = layer ? Wih1 : Wih0;
  const float* Whh = layer ? Whh1 : Whh0;
  const float* bih = layer ? bih1 : bih0;
  const float* bhh = layer ? bhh1 : bhh0;
  int* fl_own = layer ? flags1 : flags0;

  // ---- prologue: weights -> LDS (linear, conflict-free), bias, c0 ----
  for (int idx = tid; idx < 16 * 1024; idx += 512) {
    const int row = idx >> 10;           // 0..15 = gate*4 + jj
    const int k   = idx & 1023;
    const int rg  = ((row >> 2) << 9) + j0 + (row & 3);
    Wsh[(row << 10) + k] = (k < 512) ? Wih[(rg << 9) + k] : Whh[(rg << 9) + (k - 512)];
  }
  float creg = 0.0f;
  float bias_[4] = {0.f, 0.f, 0.f, 0.f};
  if (tid < 128) {
    const int jj = tid & 3;
    creg = c0c[layer * 512 + j0 + jj];
#pragma unroll
    for (int g = 0; g < 4; ++g) {
      const int rg = (g << 9) + j0 + jj;
      bias_[g] = bih[rg] + bhh[rg];
    }
  }

  // chunk DMA: per wave, 4 batch-rows (1024 B each, linear both sides). 4 vmcnt
  // slots per issue per thread.
  auto issue = [&](int slot, int c, int ss) {
    float* sp = ubuf + (slot << 13);
#pragma unroll
    for (int i = 0; i < 4; ++i) {
      const int b = (i << 3) + wg;
      float* l = sp + (b << 8);
      if (layer == 0) {
        if (c < 2)        GLL_P(x + ((size_t)((b << 11) + ss) << 9) + (c << 8) + k4, l);
        else if (ss == 0) GLL_P(h0c + ((c - 2) << 8) + k4, l);
        else              GLL_C(ring + (size_t)((((ss - 1) & 3) << 5) + b) * 512 + ((c - 2) << 8) + k4, l);
      } else {
        if (c < 2)        GLL_C(ring + (size_t)(((ss & 3) << 5) + b) * 512 + (c << 8) + k4, l);
        else if (ss == 0) GLL_P(h0c + 512 + ((c - 2) << 8) + k4, l);
        else              GLL_C(ring1 + (size_t)((((ss - 1) & 3) << 5) + b) * 512 + ((c - 2) << 8) + k4, l);
      }
    }
  };

  float red[64];  // 8 rows x 8 batches partials (this lane's k-slice)
  auto compute = [&](int slot, int c, bool first) {
    const float* sp = ubuf + (slot << 13);
    const float* wp = Wsh + (c << 8);
    f32x4 w[8];
#pragma unroll
    for (int i = 0; i < 8; ++i) w[i] = *(const f32x4*)(wp + ((R0 + i) << 10) + k4);
#pragma unroll
    for (int half = 0; half < 2; ++half) {
      f32x4 u[4];
#pragma unroll
      for (int i = 0; i < 4; ++i)
        u[i] = *(const f32x4*)(sp + ((B0 + (half << 2) + i) << 8) + k4);
#pragma unroll
      for (int ri = 0; ri < 8; ++ri)
#pragma unroll
        for (int i = 0; i < 4; ++i) {
          const int bi = (half << 2) + i;
          float t = first ? u[i].x * w[ri].x
                          : fmaf(u[i].x, w[ri].x, red[(ri << 3) + bi]);
          t = fmaf(u[i].y, w[ri].y, t);
          t = fmaf(u[i].z, w[ri].z, t);
          red[(ri << 3) + bi] = fmaf(u[i].w, w[ri].w, t);
        }
    }
  };

  asm volatile("s_waitcnt vmcnt(0) lgkmcnt(0)" ::: "memory");
  __builtin_amdgcn_sched_barrier(0);
  __builtin_amdgcn_s_barrier();   // Wsh visible

  if (layer == 1) {  // y0[0] must exist before c0/c1(s=0) ring DMA
    poll_lane(flags0 + lane, 1);
    poll_lane(flags0 + 64 + lane, 1);
  }
  issue(0, 0, 0);
  issue(1, 1, 0);

#pragma unroll 1
  for (int s = 0; s < TT; ++s) {
    // ---- chunk 0
    VMCNT4(); BAR();               // c0 landed everywhere (c1 in flight)
    compute(0, 0, true);
    BAR();                         // slot A free
    if (s > 0) {                   // h[s-1] producers (all waves poll: each then DMAs)
      poll_lane(fl_own + lane, s);
      poll_lane(fl_own + 64 + lane, s);
    }
    issue(0, 2, s);
    // ---- chunk 1
    VMCNT4(); BAR();
    compute(1, 1, false);
    BAR();                         // slot B free
    issue(1, 3, s);
    // ---- chunk 2
    VMCNT4(); BAR();
    compute(0, 2, false);
    BAR();                         // slot A free
    if (s + 1 < TT) {
      if (layer == 1) {            // y0[s+1] ready before next-step c0/c1 DMA
        poll_lane(flags0 + lane, s + 2);
        poll_lane(flags0 + 64 + lane, s + 2);
      }
      issue(0, 0, s + 1);
      VMCNT4();                    // c3 landed (c0' in flight)
    } else {
      VMCNT0();                    // last step: drain c3
    }
    BAR();
    // ---- chunk 3
    compute(1, 3, false);

    // butterfly reduce-with-redistribution: lane m ends owning gate m
#pragma unroll
    for (int k = 0; k < 6; ++k) {
      const int bit = 1 << k;
      const bool hi = (lane & bit) != 0;
#pragma unroll
      for (int j = 0; j < (32 >> k); ++j) {
        const float a = red[2 * j], b = red[2 * j + 1];
        const float snd = hi ? a : b;
        const float rcv = __shfl_xor(snd, bit, 64);
        red[j] = (hi ? b : a) + rcv;
      }
    }
    // ring backpressure: L1 must be past the slot we are about to overwrite
    if (layer == 0 && s >= RING && tid < 128)
      poll_lane(flags1 + tid, s - RING + 1);
    gbuf[(R0 + (lane >> 3)) * 33 + (B0 + (lane & 7))] = red[0];
    LGKM0(); BAR();                // gbuf visible; slot B free
    if (s + 1 < TT) issue(1, 1, s + 1);

    // ---- elementwise cell + h exchange
    if (tid < 128) {
      const int jj = tid & 3;
      const int b  = tid >> 2;
      const float gi = gbuf[jj * 33 + b]        + bias_[0];
      const float gf = gbuf[(4 + jj) * 33 + b]  + bias_[1];
      const float gg = gbuf[(8 + jj) * 33 + b]  + bias_[2];
      const float go = gbuf[(12 + jj) * 33 + b] + bias_[3];
      const float cn = sigf(gf) * creg + sigf(gi) * tanh_(gg);
      const float hn = sigf(go) * tanh_(cn);
      creg = cn;
      const int j = j0 + jj;
      if (layer == 0) {
        st_coh(ring + (size_t)(((s & 3) << 5) + b) * 512 + j, hn);
        if (s == TT - 1) out[HFO + (size_t)(b << 9) + j] = hn;
      } else {
        out[((size_t)((b << 11) + s) << 9) + j] = hn;
        st_coh(ring1 + (size_t)(((s & 3) << 5) + b) * 512 + j, hn);
        if (s == TT - 1) out[HFO + (size_t)((32 + b) << 9) + j] = hn;
      }
      asm volatile("s_waitcnt vmcnt(0)" ::: "memory");  // h stores at coherence point
    }
    __builtin_amdgcn_sched_barrier(0);
    BAR();                          // all 128 cell threads' drains certified
    if (tid == 0) st_flag(fl_own + lb, s + 1);
  }

  if (tid < 128)
    out[CFO + (size_t)(((layer << 5) + (tid >> 2)) << 9) + j0 + (tid & 3)] = creg;
}

extern "C" void kernel_launch(void* const* d_in, const int* in_sizes, int n_in,
                              void* d_out, int out_size, void* d_ws, size_t ws_size,
                              hipStream_t stream) {
  (void)in_sizes; (void)n_in; (void)out_size; (void)ws_size;
  const float* x    = (const float*)d_in[0];
  const float* Wih0 = (const float*)d_in[1];
  const float* Whh0 = (const float*)d_in[2];
  const float* bih0 = (const float*)d_in[3];
  const float* bhh0 = (const float*)d_in[4];
  const float* Wih1 = (const float*)d_in[5];
  const float* Whh1 = (const float*)d_in[6];
  const float* bih1 = (const float*)d_in[7];
  const float* bhh1 = (const float*)d_in[8];
  const float* h0   = (const float*)d_in[9];
  const float* c0   = (const float*)d_in[10];

  float* out    = (float*)d_out;
  float* ring   = (float*)d_ws;                            // 256 KB
  float* ring1  = (float*)((char*)d_ws + (256 << 10));     // 256 KB
  int*   flags0 = (int*)((char*)d_ws + (512 << 10));       // 128 ints, dense
  int*   flags1 = (int*)((char*)d_ws + (512 << 10) + 512); // 128 ints, dense

  // flags must be zero every call (graph replays don't re-poison)
  hipMemsetAsync(flags0, 0, 1024, stream);

  hipLaunchKernelGGL(lstm_persist, dim3(2 * NBLK), dim3(512), 0, stream,
                     x, Wih0, Whh0, bih0, bhh0, Wih1, Whh1, bih1, bhh1,
                     h0, c0, out, ring, ring1, flags0, flags1);
}

// Round 9
// 23111.145 us; speedup vs baseline: 1.3549x; 1.3549x over previous
//
#include <hip/hip_runtime.h>

namespace {
constexpr int TT   = 2048;
constexpr int NBLK = 128;
constexpr size_t YSZ = (size_t)32 * TT * 512;
constexpr size_t HFO = YSZ;
constexpr size_t CFO = YSZ + (size_t)2 * 32 * 512;
}

typedef float f32x4 __attribute__((ext_vector_type(4)));

__device__ __forceinline__ float sigf(float v)  { return 1.0f / (1.0f + __expf(-v)); }
__device__ __forceinline__ float tanh_(float v) { return 1.0f - 2.0f / (__expf(2.0f * v) + 1.0f); }

__device__ __forceinline__ void st_coh(float* p, float v) {
  __hip_atomic_store(p, v, __ATOMIC_RELAXED, __HIP_MEMORY_SCOPE_AGENT);
}
__device__ __forceinline__ void st_flag(int* p, int v) {
  __hip_atomic_store(p, v, __ATOMIC_RELAXED, __HIP_MEMORY_SCOPE_AGENT);
}
// lane covers flags[lane] and flags[64+lane]; both loads in flight per iter.
__device__ __forceinline__ void poll2(const int* f, int need) {
  while (true) {
    const int a = __hip_atomic_load(f,      __ATOMIC_RELAXED, __HIP_MEMORY_SCOPE_AGENT);
    const int b = __hip_atomic_load(f + 64, __ATOMIC_RELAXED, __HIP_MEMORY_SCOPE_AGENT);
    if (a >= need && b >= need) break;
    __builtin_amdgcn_s_sleep(1);
  }
}

// global->LDS DMA, 16 B/lane; LDS dst = wave-uniform base + lane*16 (linear).
// _C: aux=0x11 (SC0|SC1) -> bypass L1/L2, read the shared coherence point.
#define GLL_P(g, l) __builtin_amdgcn_global_load_lds(                         \
    (const __attribute__((address_space(1))) void*)(g),                       \
    (__attribute__((address_space(3))) void*)(l), 16, 0, 0)
#define GLL_C(g, l) __builtin_amdgcn_global_load_lds(                         \
    (const __attribute__((address_space(1))) void*)(g),                       \
    (__attribute__((address_space(3))) void*)(l), 16, 0, 0x11)

#define VMCNT4() do { asm volatile("s_waitcnt vmcnt(4)" ::: "memory"); __builtin_amdgcn_sched_barrier(0); } while (0)
#define VMCNT0() do { asm volatile("s_waitcnt vmcnt(0)" ::: "memory"); __builtin_amdgcn_sched_barrier(0); } while (0)
#define LGKM0()  do { asm volatile("s_waitcnt lgkmcnt(0)" ::: "memory"); __builtin_amdgcn_sched_barrier(0); } while (0)
#define BAR()    do { __builtin_amdgcn_s_barrier(); __builtin_amdgcn_sched_barrier(0); } while (0)

__global__ __launch_bounds__(512, 1)
void lstm_persist(
    const float* __restrict__ x,
    const float* __restrict__ Wih0, const float* __restrict__ Whh0,
    const float* __restrict__ bih0, const float* __restrict__ bhh0,
    const float* __restrict__ Wih1, const float* __restrict__ Whh1,
    const float* __restrict__ bih1, const float* __restrict__ bhh1,
    const float* __restrict__ h0c, const float* __restrict__ c0c,
    float* __restrict__ out, float* __restrict__ ring, float* __restrict__ ring1,
    int* __restrict__ flags0, int* __restrict__ flags1)
{
  // LDS: W' 64 KB + 2 slots 2x32 KB + gbuf/xgb ~6.3 KB = ~134.3 KB (1 block/CU).
  __shared__ __align__(16) float Wsh[16 * 1024];
  __shared__ __align__(16) float ubuf[2 * 32 * 256];
  __shared__ __align__(16) float gbuf[16 * 33];
  __shared__ __align__(16) float xgb[2][16 * 33];   // slack-half gate partials, parity by step

  const int tid   = (int)threadIdx.x;
  const int layer = (int)(blockIdx.x >> 7);
  const int lb    = (int)(blockIdx.x & (NBLK - 1));
  const int j0    = lb << 2;
  const int lane  = tid & 63;
  const int wg    = tid >> 6;          // wave 0..7
  const int k4    = lane << 2;         // lane's f32x4 within a 256-k chunk
  const int R0    = (wg & 1) << 3;     // 8-row group
  const int B0    = (wg >> 1) << 3;    // 8-batch group

  const float* Wih = layer ? Wih1 : Wih0;
  const float* Whh = layer ? Whh1 : Whh0;
  const float* bih = layer ? bih1 : bih0;
  const float* bhh = layer ? bhh1 : bhh0;
  int* fl_own = layer ? flags1 : flags0;
  // W-column bases: A = critical half (L0: h0 cols 512+, L1: y0 cols 0+)
  //                 B = slack half    (L0: x  cols 0+,  L1: h1 cols 512+)
  const int awb = layer ? 0 : 512;
  const int bwb = layer ? 512 : 0;

  // ---- prologue: weights -> LDS (linear), bias, c0 ----
  for (int idx = tid; idx < 16 * 1024; idx += 512) {
    const int row = idx >> 10;           // 0..15 = gate*4 + jj
    const int k   = idx & 1023;
    const int rg  = ((row >> 2) << 9) + j0 + (row & 3);
    Wsh[(row << 10) + k] = (k < 512) ? Wih[(rg << 9) + k] : Whh[(rg << 9) + (k - 512)];
  }
  float creg = 0.0f;
  float bias_[4] = {0.f, 0.f, 0.f, 0.f};
  if (tid < 128) {
    const int jj = tid & 3;
    creg = c0c[layer * 512 + j0 + jj];
#pragma unroll
    for (int g = 0; g < 4; ++g) {
      const int rg = (g << 9) + j0 + jj;
      bias_[g] = bih[rg] + bhh[rg];
    }
  }

  // A half for step ss: L0 = h0[ss-1] (h0c at ss==0), L1 = y0[ss]. 2 chunks -> slots 0,1.
  auto issueA = [&](int ss) {
#pragma unroll
    for (int c = 0; c < 2; ++c) {
      float* sp = ubuf + (c << 13);
#pragma unroll
      for (int i = 0; i < 4; ++i) {
        const int b = (i << 3) + wg;
        float* l = sp + (b << 8);
        if (layer == 0) {
          if (ss == 0) GLL_P(h0c + (c << 8) + k4, l);
          else         GLL_C(ring + (size_t)((((ss - 1) & 3) << 5) + b) * 512 + (c << 8) + k4, l);
        } else {
          GLL_C(ring + (size_t)(((ss & 3) << 5) + b) * 512 + (c << 8) + k4, l);
        }
      }
    }
  };
  // B half feeding step sn: L0 = x[sn], L1 = h1[sn-1] (h0c at sn==0).
  auto issueB = [&](int sn) {
#pragma unroll
    for (int c = 0; c < 2; ++c) {
      float* sp = ubuf + (c << 13);
#pragma unroll
      for (int i = 0; i < 4; ++i) {
        const int b = (i << 3) + wg;
        float* l = sp + (b << 8);
        if (layer == 0)      GLL_P(x + ((size_t)((b << 11) + sn) << 9) + (c << 8) + k4, l);
        else if (sn == 0)    GLL_P(h0c + 512 + (c << 8) + k4, l);
        else                 GLL_C(ring1 + (size_t)((((sn - 1) & 3) << 5) + b) * 512 + (c << 8) + k4, l);
      }
    }
  };

  float red[64];  // 8 rows x 8 batches partials (lane's k-slice)
  auto compute = [&](int slot, int wcol, bool first) {
    const float* sp = ubuf + (slot << 13);
    const float* wp = Wsh + wcol;
    f32x4 w[8];
#pragma unroll
    for (int i = 0; i < 8; ++i) w[i] = *(const f32x4*)(wp + ((R0 + i) << 10) + k4);
#pragma unroll
    for (int half = 0; half < 2; ++half) {
      f32x4 u[4];
#pragma unroll
      for (int i = 0; i < 4; ++i)
        u[i] = *(const f32x4*)(sp + ((B0 + (half << 2) + i) << 8) + k4);
#pragma unroll
      for (int ri = 0; ri < 8; ++ri)
#pragma unroll
        for (int i = 0; i < 4; ++i) {
          const int bi = (half << 2) + i;
          float t = first ? u[i].x * w[ri].x
                          : fmaf(u[i].x, w[ri].x, red[(ri << 3) + bi]);
          t = fmaf(u[i].y, w[ri].y, t);
          t = fmaf(u[i].z, w[ri].z, t);
          red[(ri << 3) + bi] = fmaf(u[i].w, w[ri].w, t);
        }
    }
  };
  // butterfly: lane m ends owning gate-row m's (8b) slice; store to dst
  auto reduce_store = [&](float* dst) {
#pragma unroll
    for (int k = 0; k < 6; ++k) {
      const int bit = 1 << k;
      const bool hi = (lane & bit) != 0;
#pragma unroll
      for (int j = 0; j < (32 >> k); ++j) {
        const float a = red[2 * j], b = red[2 * j + 1];
        const float snd = hi ? a : b;
        const float rcv = __shfl_xor(snd, bit, 64);
        red[j] = (hi ? b : a) + rcv;
      }
    }
    dst[(R0 + (lane >> 3)) * 33 + (B0 + (lane & 7))] = red[0];
  };

  asm volatile("s_waitcnt vmcnt(0) lgkmcnt(0)" ::: "memory");
  __builtin_amdgcn_sched_barrier(0);
  __builtin_amdgcn_s_barrier();   // Wsh visible

  // ---- prologue phase B for step 0 (L0: x[0]; L1: h1 init) ----
  issueB(0);
  VMCNT4(); BAR(); compute(0, bwb, true);
  VMCNT0(); BAR(); compute(1, bwb + 256, false);
  reduce_store(&xgb[0][0]);
  if (layer == 1) poll2(flags0 + lane, 1);   // y0[0] ready
  LGKM0(); BAR();                            // slot reads done; xgb[0] written
  issueA(0);

#pragma unroll 1
  for (int s = 0; s < TT; ++s) {
    // ---------- phase A: critical half ----------
    VMCNT4(); BAR(); compute(0, awb, true);
    VMCNT0(); BAR(); compute(1, awb + 256, false);
    reduce_store(gbuf);
    LGKM0(); BAR();                          // gbuf visible
    if (tid < 128) {
      const int jj = tid & 3;
      const int b  = tid >> 2;
      const float* xg = &xgb[s & 1][0];
      const float gi = gbuf[jj * 33 + b]        + xg[jj * 33 + b]        + bias_[0];
      const float gf = gbuf[(4 + jj) * 33 + b]  + xg[(4 + jj) * 33 + b]  + bias_[1];
      const float gg = gbuf[(8 + jj) * 33 + b]  + xg[(8 + jj) * 33 + b]  + bias_[2];
      const float go = gbuf[(12 + jj) * 33 + b] + xg[(12 + jj) * 33 + b] + bias_[3];
      const float cn = sigf(gf) * creg + sigf(gi) * tanh_(gg);
      const float hn = sigf(go) * tanh_(cn);
      creg = cn;
      const int j = j0 + jj;
      if (layer == 0) {
        st_coh(ring + (size_t)(((s & 3) << 5) + b) * 512 + j, hn);
        if (s == TT - 1) out[HFO + (size_t)(b << 9) + j] = hn;
      } else {
        out[((size_t)((b << 11) + s) << 9) + j] = hn;
        st_coh(ring1 + (size_t)(((s & 3) << 5) + b) * 512 + j, hn);
        if (s == TT - 1) out[HFO + (size_t)((32 + b) << 9) + j] = hn;
      }
      asm volatile("s_waitcnt vmcnt(0)" ::: "memory");  // h at coherence point
    }
    __builtin_amdgcn_sched_barrier(0);
    BAR();
    if (tid == 0) st_flag(fl_own + lb, s + 1);

    // ---------- phase B: slack half for step s+1 ----------
    if (s + 1 < TT) {
      if (layer == 1) poll2(flags1 + lane, s + 1);  // own-layer h1[s] exchange
      issueB(s + 1);
      VMCNT4(); BAR(); compute(0, bwb, true);
      VMCNT0(); BAR(); compute(1, bwb + 256, false);
      reduce_store(&xgb[(s + 1) & 1][0]);
      if (layer == 0) {
        if (s >= 3) poll2(flags1 + lane, s - 2);    // ring backpressure for h0[s+1] store
        poll2(flags0 + lane, s + 1);                // peers' h0[s] ready
      } else {
        poll2(flags0 + lane, s + 2);                // y0[s+1] ready
      }
      LGKM0(); BAR();                               // slot reads done; xgb written
      issueA(s + 1);
    }
  }

  if (tid < 128)
    out[CFO + (size_t)(((layer << 5) + (tid >> 2)) << 9) + j0 + (tid & 3)] = creg;
}

extern "C" void kernel_launch(void* const* d_in, const int* in_sizes, int n_in,
                              void* d_out, int out_size, void* d_ws, size_t ws_size,
                              hipStream_t stream) {
  (void)in_sizes; (void)n_in; (void)out_size; (void)ws_size;
  const float* x    = (const float*)d_in[0];
  const float* Wih0 = (const float*)d_in[1];
  const float* Whh0 = (const float*)d_in[2];
  const float* bih0 = (const float*)d_in[3];
  const float* bhh0 = (const float*)d_in[4];
  const float* Wih1 = (const float*)d_in[5];
  const float* Whh1 = (const float*)d_in[6];
  const float* bih1 = (const float*)d_in[7];
  const float* bhh1 = (const float*)d_in[8];
  const float* h0   = (const float*)d_in[9];
  const float* c0   = (const float*)d_in[10];

  float* out    = (float*)d_out;
  float* ring   = (float*)d_ws;                            // 256 KB (h0/y0, 4 slots)
  float* ring1  = (float*)((char*)d_ws + (256 << 10));     // 256 KB (h1, 4 slots)
  int*   flags0 = (int*)((char*)d_ws + (512 << 10));       // 128 ints, dense
  int*   flags1 = (int*)((char*)d_ws + (512 << 10) + 512); // 128 ints, dense

  // flags must be zero every call (graph replays don't re-poison)
  hipMemsetAsync(flags0, 0, 1024, stream);

  hipLaunchKernelGGL(lstm_persist, dim3(2 * NBLK), dim3(512), 0, stream,
                     x, Wih0, Whh0, bih0, bhh0, Wih1, Whh1, bih1, bhh1,
                     h0, c0, out, ring, ring1, flags0, flags1);
}

// Round 10
// 16696.867 us; speedup vs baseline: 1.8754x; 1.3842x over previous
//
#include <hip/hip_runtime.h>

namespace {
constexpr int TT   = 2048;
constexpr int NBLK = 128;
constexpr size_t YSZ = (size_t)32 * TT * 512;
constexpr size_t HFO = YSZ;
constexpr size_t CFO = YSZ + (size_t)2 * 32 * 512;
}

typedef float f32x4 __attribute__((ext_vector_type(4)));
typedef short s16x8 __attribute__((ext_vector_type(8)));

__device__ __forceinline__ float sigf(float v)  { return 1.0f / (1.0f + __expf(-v)); }
__device__ __forceinline__ float tanh_(float v) { return 1.0f - 2.0f / (__expf(2.0f * v) + 1.0f); }
// f32 -> bf16 round-to-nearest-even (bit trick; scalar, order-safe)
__device__ __forceinline__ short f2bf(float v) {
  unsigned u = __float_as_uint(v);
  u += 0x7FFFu + ((u >> 16) & 1u);
  return (short)(u >> 16);
}
__device__ __forceinline__ float bf2f(short h) {
  return __uint_as_float(((unsigned)(unsigned short)h) << 16);
}
__device__ __forceinline__ void st_short_coh(void* p, int v) {
  asm volatile("global_store_short %0, %1, off sc1" :: "v"(p), "v"(v) : "memory");
}
// wave polls 128 dense flags (2 per lane)
__device__ __forceinline__ void poll2(const int* f, int need) {
  while (true) {
    const int a = __hip_atomic_load(f,      __ATOMIC_RELAXED, __HIP_MEMORY_SCOPE_AGENT);
    const int b = __hip_atomic_load(f + 64, __ATOMIC_RELAXED, __HIP_MEMORY_SCOPE_AGENT);
    if (a >= need && b >= need) break;
    __builtin_amdgcn_s_sleep(1);
  }
}

// global->LDS DMA 16B/lane; LDS dst wave-uniform+lane*16 (linear); per-lane global src
#define GLLP(g, l) __builtin_amdgcn_global_load_lds(                          \
    (const __attribute__((address_space(1))) void*)(g),                       \
    (__attribute__((address_space(3))) void*)(l), 16, 0, 0)
#define GLLC(g, l) __builtin_amdgcn_global_load_lds(                          \
    (const __attribute__((address_space(1))) void*)(g),                       \
    (__attribute__((address_space(3))) void*)(l), 16, 0, 0x11)

#define VMCNT0() do { asm volatile("s_waitcnt vmcnt(0)" ::: "memory"); __builtin_amdgcn_sched_barrier(0); } while (0)
#define LGKM0()  do { asm volatile("s_waitcnt lgkmcnt(0)" ::: "memory"); __builtin_amdgcn_sched_barrier(0); } while (0)
#define BAR()    do { __builtin_amdgcn_s_barrier(); __builtin_amdgcn_sched_barrier(0); } while (0)

__global__ __launch_bounds__(512)
void lstm_persist(
    const float* __restrict__ x,
    const float* __restrict__ Wih0, const float* __restrict__ Whh0,
    const float* __restrict__ bih0, const float* __restrict__ bhh0,
    const float* __restrict__ Wih1, const float* __restrict__ Whh1,
    const float* __restrict__ bih1, const float* __restrict__ bhh1,
    const float* __restrict__ h0c, const float* __restrict__ c0c,
    float* __restrict__ out,
    short* __restrict__ r0hi, short* __restrict__ r0lo,
    short* __restrict__ r1hi, short* __restrict__ r1lo,
    int* __restrict__ flags0, int* __restrict__ flags1)
{
  // LDS: W planes 64 KB + stage 64 KB + gbuf/xgb ~6.3 KB = ~134 KB (1 block/CU)
  __shared__ __align__(16) short Whi[16 * 1024];   // XOR-swizzled rows
  __shared__ __align__(16) short Wlo[16 * 1024];
  __shared__ __align__(16) float stage[32 * 512];  // union: bf16 planes (hi 32KB | lo 32KB) OR [32][512] f32
  __shared__ __align__(16) float gbuf[16 * 33];
  __shared__ __align__(16) float xgb[2][16 * 33];

  const int tid   = (int)threadIdx.x;
  const int layer = (int)(blockIdx.x >> 7);
  const int lb    = (int)(blockIdx.x & (NBLK - 1));
  const int j0    = lb << 2;
  const int lane  = tid & 63;
  const int wg    = tid >> 6;         // wave 0..7; waves 0,1 = MFMA+cell; 2,3 = pollers
  char* stageb = (char*)stage;

  const float* Wih = layer ? Wih1 : Wih0;
  const float* Whh = layer ? Whh1 : Whh0;
  const float* bih = layer ? bih1 : bih0;
  const float* bhh = layer ? bhh1 : bhh0;
  short* rwhi = layer ? r1hi : r0hi;  // own-layer h planes (producer side)
  short* rwlo = layer ? r1lo : r0lo;
  int* fl_own = layer ? flags1 : flags0;
  const int awb = layer ? 0 : 512;    // critical-half W col base (L0: h->Whh, L1: y0->Wih)
  const int bwb = layer ? 512 : 0;    // slack-half W col base

  // ---- prologue: W -> bf16 hi/lo planes in LDS (swizzled), bias, c0 ----
  for (int idx = tid; idx < 16 * 1024; idx += 512) {
    const int row = idx >> 10;        // 0..15 = gate*4 + jj
    const int k   = idx & 1023;
    const int rg  = ((row >> 2) << 9) + j0 + (row & 3);
    const float v = (k < 512) ? Wih[(rg << 9) + k] : Whh[(rg << 9) + (k - 512)];
    const short h = f2bf(v);
    const short l = f2bf(v - bf2f(h));
    const int byte = (row << 11) + ((k << 1) ^ ((row & 7) << 4));
    *(short*)((char*)Whi + byte) = h;
    *(short*)((char*)Wlo + byte) = l;
  }
  float creg = 0.0f;
  float bias_[4] = {0.f, 0.f, 0.f, 0.f};
  if (tid < 128) {
    const int jj = tid & 3;
    creg = c0c[layer * 512 + j0 + jj];
#pragma unroll
    for (int g = 0; g < 4; ++g) {
      const int rg = (g << 9) + j0 + jj;
      bias_[g] = bih[rg] + bhh[rg];
    }
  }

  // ---- staging lambdas (8 GLL per thread each) ----
  // bf16 planes [32][512] from a ring slot (coherent)
  auto stage_planes = [&](const short* rh, const short* rl) {
#pragma unroll
    for (int i = 0; i < 4; ++i) {
      const int b = (i << 3) + wg;
      const int off = (b << 10) + ((lane << 4) ^ ((b & 7) << 4));
      GLLC((const char*)rh + off, stageb + (b << 10));
      GLLC((const char*)rl + off, stageb + 32768 + (b << 10));
    }
  };
  // fp32 [32][512] from x[.,sn,.] (per-batch rows)
  auto stage_x = [&](int sn) {
#pragma unroll
    for (int i = 0; i < 8; ++i) {
      const int u = (wg << 3) + i;
      const int b = u >> 1, half = (u & 1) << 10;
      const char* src = (const char*)x + ((size_t)(b * 2048 + sn) << 11) + half
                        + ((lane << 4) ^ ((b & 7) << 4));
      GLLP(src, stageb + (b << 11) + half);
    }
  };
  // fp32 [32][512] broadcast of a 512-float vector (h0/c0 initial state)
  auto stage_bcast = [&](const float* p) {
#pragma unroll
    for (int i = 0; i < 8; ++i) {
      const int u = (wg << 3) + i;
      const int b = u >> 1, half = (u & 1) << 10;
      GLLP((const char*)p + half + ((lane << 4) ^ ((b & 7) << 4)),
           stageb + (b << 11) + half);
    }
  };

  // ---- MFMA: D[16 rows x 16 batch] over K=512, bf16x3 (waves 0,1 only) ----
  auto do_mfma = [&](int wbase, bool cvt, float* dst) {
    f32x4 a0 = {0.f, 0.f, 0.f, 0.f}, a1 = {0.f, 0.f, 0.f, 0.f};
    const int arow = lane & 15;
    const int kg   = lane >> 4;
    const int bb   = (wg << 4) + (lane & 15);
    const int wsz  = (arow & 7) << 4;
    const int usz  = (bb & 7) << 4;
#pragma unroll
    for (int ks = 0; ks < 16; ++ks) {
      const int ku = ks * 32 + (kg << 3);           // k within staged half
      const int wb = ((wbase + ku) << 1) ^ wsz;     // W byte-in-row
      const s16x8 ah = *(const s16x8*)((const char*)Whi + (arow << 11) + wb);
      const s16x8 al = *(const s16x8*)((const char*)Wlo + (arow << 11) + wb);
      s16x8 bh, bl;
      if (!cvt) {
        const int ub = ((ku << 1) ^ usz);
        bh = *(const s16x8*)(stageb + (bb << 10) + ub);
        bl = *(const s16x8*)(stageb + 32768 + (bb << 10) + ub);
      } else {
        const f32x4 p = *(const f32x4*)(stageb + (bb << 11) + ((ku << 2) ^ usz));
        const f32x4 q = *(const f32x4*)(stageb + (bb << 11) + (((ku + 4) << 2) ^ usz));
        const float pv[8] = {p.x, p.y, p.z, p.w, q.x, q.y, q.z, q.w};
#pragma unroll
        for (int j = 0; j < 8; ++j) {
          const short h = f2bf(pv[j]);
          bh[j] = h;
          bl[j] = f2bf(pv[j] - bf2f(h));
        }
      }
      if (ks & 1) {
        a1 = __builtin_amdgcn_mfma_f32_16x16x32_bf16(ah, bh, a1, 0, 0, 0);
        a1 = __builtin_amdgcn_mfma_f32_16x16x32_bf16(ah, bl, a1, 0, 0, 0);
        a1 = __builtin_amdgcn_mfma_f32_16x16x32_bf16(al, bh, a1, 0, 0, 0);
      } else {
        a0 = __builtin_amdgcn_mfma_f32_16x16x32_bf16(ah, bh, a0, 0, 0, 0);
        a0 = __builtin_amdgcn_mfma_f32_16x16x32_bf16(ah, bl, a0, 0, 0, 0);
        a0 = __builtin_amdgcn_mfma_f32_16x16x32_bf16(al, bh, a0, 0, 0, 0);
      }
    }
    const f32x4 c = a0 + a1;
    // C layout: row=(lane>>4)*4+r, col=lane&15 (m89); col -> batch within tile wg
#pragma unroll
    for (int r = 0; r < 4; ++r)
      dst[((kg << 2) + r) * 33 + (wg << 4) + (lane & 15)] = c[r];
    LGKM0();  // same-wave: writes visible to this wave's cell reads
  };

  VMCNT0(); LGKM0(); BAR();          // W planes + bias ready

  // ---- prologue phase B(0): slack half of step 0 -> xgb[0] ----
  if (layer == 0) stage_x(0); else stage_bcast(h0c + 512);
  VMCNT0(); BAR();
  if (wg < 2) do_mfma(bwb, true, &xgb[0][0]);
  if (layer == 1 && wg == 2) poll2(flags0 + lane, 1);  // y0[0] for A(0)
  BAR();
  // ---- stage A(0) ----
  if (layer == 0) stage_bcast(h0c);
  else            stage_planes(r0hi, r0lo);            // slot 0
  VMCNT0(); BAR();

#pragma unroll 1
  for (int s = 0; s < TT; ++s) {
    const int slot = s & 3;
    // ---------- phase A: critical half ----------
    if (wg < 2) do_mfma(awb, layer == 0 && s == 0, gbuf);
    if (tid < 128) {
      const int jj = tid & 3;
      const int b  = tid >> 2;
      const float* xg = &xgb[s & 1][0];
      const float gi = gbuf[jj * 33 + b]        + xg[jj * 33 + b]        + bias_[0];
      const float gf = gbuf[(4 + jj) * 33 + b]  + xg[(4 + jj) * 33 + b]  + bias_[1];
      const float gg = gbuf[(8 + jj) * 33 + b]  + xg[(8 + jj) * 33 + b]  + bias_[2];
      const float go = gbuf[(12 + jj) * 33 + b] + xg[(12 + jj) * 33 + b] + bias_[3];
      const float cn = sigf(gf) * creg + sigf(gi) * tanh_(gg);
      const float hn = sigf(go) * tanh_(cn);
      creg = cn;
      const int j = j0 + jj;
      const short hb = f2bf(hn);
      const short lbh = f2bf(hn - bf2f(hb));
      short* ph = rwhi + (((slot << 5) + b) << 9) + j;
      short* pl = rwlo + (((slot << 5) + b) << 9) + j;
      st_short_coh(ph, (int)hb);
      st_short_coh(pl, (int)lbh);
      if (layer == 1) out[((size_t)((b << 11) + s) << 9) + j] = hn;
      if (s == TT - 1) out[HFO + (size_t)(((layer << 5) + b) << 9) + j] = hn;
      asm volatile("s_waitcnt vmcnt(0)" ::: "memory");   // h planes at coherence point
    }
    __builtin_amdgcn_sched_barrier(0);
    BAR();
    if (tid == 0)
      __hip_atomic_store(fl_own + lb, s + 1, __ATOMIC_RELAXED, __HIP_MEMORY_SCOPE_AGENT);

    // ---------- phase B: slack half for step s+1 + staging ----------
    if (s + 1 < TT) {
      if (layer == 1) {                       // own h1[s] planes must be complete
        if (wg == 2) poll2(flags1 + lane, s + 1);
        BAR();
      }
      if (layer == 0) stage_x(s + 1);
      else            stage_planes(r1hi + (slot << 14), r1lo + (slot << 14));
      VMCNT0(); BAR();
      if (wg < 2) do_mfma(bwb, layer == 0, &xgb[(s + 1) & 1][0]);
      if (wg == 2) poll2(flags0 + lane, layer == 0 ? s + 1 : s + 2);  // A(s+1) producer
      if (wg == 3 && s >= 3) poll2(flags1 + lane, s - 2);             // ring backpressure
      BAR();
      if (layer == 0) stage_planes(r0hi + (slot << 14), r0lo + (slot << 14));
      else            stage_planes(r0hi + (((s + 1) & 3) << 14), r0lo + (((s + 1) & 3) << 14));
      VMCNT0(); BAR();
    }
  }

  if (tid < 128)
    out[CFO + (size_t)(((layer << 5) + (tid >> 2)) << 9) + j0 + (tid & 3)] = creg;
}

extern "C" void kernel_launch(void* const* d_in, const int* in_sizes, int n_in,
                              void* d_out, int out_size, void* d_ws, size_t ws_size,
                              hipStream_t stream) {
  (void)in_sizes; (void)n_in; (void)out_size; (void)ws_size;
  const float* x    = (const float*)d_in[0];
  const float* Wih0 = (const float*)d_in[1];
  const float* Whh0 = (const float*)d_in[2];
  const float* bih0 = (const float*)d_in[3];
  const float* bhh0 = (const float*)d_in[4];
  const float* Wih1 = (const float*)d_in[5];
  const float* Whh1 = (const float*)d_in[6];
  const float* bih1 = (const float*)d_in[7];
  const float* bhh1 = (const float*)d_in[8];
  const float* h0   = (const float*)d_in[9];
  const float* c0   = (const float*)d_in[10];

  float* out = (float*)d_out;
  // ws: 4 plane rings (4 slots x 32 b x 512) x 2B = 128 KB each; then dense flags
  short* r0hi = (short*)d_ws;
  short* r0lo = (short*)((char*)d_ws + (128 << 10));
  short* r1hi = (short*)((char*)d_ws + (256 << 10));
  short* r1lo = (short*)((char*)d_ws + (384 << 10));
  int* flags0 = (int*)((char*)d_ws + (512 << 10));
  int* flags1 = (int*)((char*)d_ws + (512 << 10) + 512);

  hipMemsetAsync(flags0, 0, 1024, stream);

  hipLaunchKernelGGL(lstm_persist, dim3(2 * NBLK), dim3(512), 0, stream,
                     x, Wih0, Whh0, bih0, bhh0, Wih1, Whh1, bih1, bhh1,
                     h0, c0, out, r0hi, r0lo, r1hi, r1lo, flags0, flags1);
}